// Round 1
// baseline (331.718 us; speedup 1.0000x reference)
//
#include <hip/hip_runtime.h>
#include <hip/hip_bf16.h>

#define D 128   // D_IN == D_OUT == 128

// ---------- utility ----------
__global__ void zero_int_kernel(int* p, int n) {
    int i = blockIdx.x * blockDim.x + threadIdx.x;
    if (i < n) p[i] = 0;
}

// ---------- degree histogram ----------
__global__ void deg_kernel(const int* __restrict__ rows, int* __restrict__ deg, int E) {
    int i = blockIdx.x * blockDim.x + threadIdx.x;
    if (i < E) atomicAdd(&deg[rows[i]], 1);
}

// ---------- norm = clip(deg,1)^-0.5 ----------
__global__ void norm_kernel(const int* __restrict__ deg, float* __restrict__ norm, int n) {
    int i = blockIdx.x * blockDim.x + threadIdx.x;
    if (i < n) {
        int d = deg[i];
        if (d < 1) d = 1;
        norm[i] = rsqrtf((float)d);
    }
}

// ---------- exclusive prefix sum of deg -> row_start[0..n] (single block) ----------
__global__ __launch_bounds__(1024) void scan_kernel(const int* __restrict__ deg,
                                                    int* __restrict__ row_start, int n) {
    __shared__ int part[1024];
    int t = threadIdx.x;
    int chunk = (n + 1023) / 1024;
    int s = t * chunk;
    int e = s + chunk; if (e > n) e = n;
    int sum = 0;
    for (int i = s; i < e; ++i) sum += deg[i];
    part[t] = sum;
    __syncthreads();
    // inclusive block scan (Hillis-Steele)
    for (int off = 1; off < 1024; off <<= 1) {
        int v = (t >= off) ? part[t - off] : 0;
        __syncthreads();
        part[t] += v;
        __syncthreads();
    }
    int run = (t > 0) ? part[t - 1] : 0;
    for (int i = s; i < e; ++i) { row_start[i] = run; run += deg[i]; }
    if (t == 1023) row_start[n] = part[1023];
}

// ---------- fill CSR buckets with column indices ----------
__global__ void fill_kernel(const int* __restrict__ rows, const int* __restrict__ cols,
                            const int* __restrict__ row_start, int* __restrict__ cursor,
                            int* __restrict__ edge_col, int E) {
    int i = blockIdx.x * blockDim.x + threadIdx.x;
    if (i < E) {
        int r = rows[i];
        int p = atomicAdd(&cursor[r], 1);
        edge_col[row_start[r] + p] = cols[i];
    }
}

// ---------- projection: h[r] = norm[r] * (f[r] @ W), fp32 ----------
#define GROWS 16
__global__ __launch_bounds__(256) void proj_kernel(const float* __restrict__ f,
                                                   const float* __restrict__ W,
                                                   const float* __restrict__ norm,
                                                   float* __restrict__ h,
                                                   int n_rows, int row_offset) {
    __shared__ float Wl[D * D];          // 64 KB
    __shared__ float Fl[GROWS][D];       // 8 KB
    int t = threadIdx.x;

    // stage W (16384 floats, float4-coalesced)
    for (int i = t * 4; i < D * D; i += 256 * 4) {
        *(float4*)&Wl[i] = *(const float4*)&W[i];
    }
    // stage 16 rows of f
    int rb = blockIdx.x * GROWS;
    for (int i = t * 4; i < GROWS * D; i += 256 * 4) {
        int r = i >> 7, k = i & (D - 1);
        int gr = rb + r;
        float4 v = make_float4(0.f, 0.f, 0.f, 0.f);
        if (gr < n_rows) v = *(const float4*)&f[(size_t)gr * D + k];
        *(float4*)&Fl[r][k] = v;
    }
    __syncthreads();

    int c  = t & (D - 1);   // output column
    int rg = t >> 7;        // row group 0/1 (8 rows each)
    float acc[8] = {0.f,0.f,0.f,0.f,0.f,0.f,0.f,0.f};
    for (int k = 0; k < D; ++k) {
        float w = Wl[k * D + c];
        #pragma unroll
        for (int i = 0; i < 8; ++i)
            acc[i] += Fl[rg * 8 + i][k] * w;   // Fl read is lane-broadcast (free)
    }
    #pragma unroll
    for (int i = 0; i < 8; ++i) {
        int gr = rb + rg * 8 + i;
        if (gr < n_rows) {
            float nv = norm[row_offset + gr];
            h[(size_t)(row_offset + gr) * D + c] = acc[i] * nv;
        }
    }
}

// ---------- aggregate: out[r] = norm[r] * sum_{e in row r} scaled_h[col[e]] ----------
__global__ __launch_bounds__(128) void agg_kernel(const int* __restrict__ row_start,
                                                  const int* __restrict__ edge_col,
                                                  const float* __restrict__ scaled_h,
                                                  const float* __restrict__ norm,
                                                  float* __restrict__ out, int n) {
    int r = blockIdx.x;
    int c = threadIdx.x;
    int s = row_start[r], e = row_start[r + 1];
    float acc = 0.f;
    for (int j = s; j < e; ++j) {
        int col = edge_col[j];                  // lane-uniform (broadcast)
        acc += scaled_h[(size_t)col * D + c];   // coalesced 512B row read
    }
    out[(size_t)r * D + c] = acc * norm[r];
}

extern "C" void kernel_launch(void* const* d_in, const int* in_sizes, int n_in,
                              void* d_out, int out_size, void* d_ws, size_t ws_size,
                              hipStream_t stream) {
    const float* drug_f    = (const float*)d_in[0];
    const float* disease_f = (const float*)d_in[1];
    const float* drug_w    = (const float*)d_in[2];
    const float* disease_w = (const float*)d_in[3];
    const int*   rows      = (const int*)d_in[4];
    const int*   cols      = (const int*)d_in[5];
    float* out = (float*)d_out;

    int n_drug = in_sizes[0] / D;
    int n_dis  = in_sizes[1] / D;
    int N = n_drug + n_dis;
    int E = in_sizes[4];

    // workspace layout (all 256B-aligned)
    char* ws = (char*)d_ws;
    size_t off = 0;
    auto alloc = [&](size_t bytes) { void* p = ws + off; off = (off + bytes + 255) & ~(size_t)255; return p; };
    int*   deg       = (int*)alloc(sizeof(int) * N);
    int*   cursor    = (int*)alloc(sizeof(int) * N);
    int*   row_start = (int*)alloc(sizeof(int) * (N + 1));
    float* norm      = (float*)alloc(sizeof(float) * N);
    int*   edge_col  = (int*)alloc(sizeof(int) * E);
    float* scaled_h  = (float*)alloc(sizeof(float) * (size_t)N * D);
    (void)ws_size; (void)out_size; (void)n_in;

    // 1) zero deg + cursor
    zero_int_kernel<<<(2 * N + 255) / 256, 256, 0, stream>>>(deg, 2 * N);  // deg & cursor contiguous? not guaranteed -> do separately
    zero_int_kernel<<<(N + 255) / 256, 256, 0, stream>>>(cursor, N);

    // 2) degrees
    deg_kernel<<<(E + 255) / 256, 256, 0, stream>>>(rows, deg, E);

    // 3) norm
    norm_kernel<<<(N + 255) / 256, 256, 0, stream>>>(deg, norm, N);

    // 4) prefix scan -> row_start
    scan_kernel<<<1, 1024, 0, stream>>>(deg, row_start, N);

    // 5) CSR fill
    fill_kernel<<<(E + 255) / 256, 256, 0, stream>>>(rows, cols, row_start, cursor, edge_col, E);

    // 6) projections (scaled by norm)
    proj_kernel<<<(n_drug + GROWS - 1) / GROWS, 256, 0, stream>>>(drug_f, drug_w, norm, scaled_h, n_drug, 0);
    proj_kernel<<<(n_dis + GROWS - 1) / GROWS, 256, 0, stream>>>(disease_f, disease_w, norm, scaled_h, n_dis, n_drug);

    // 7) aggregate
    agg_kernel<<<N, 128, 0, stream>>>(row_start, edge_col, scaled_h, norm, out, N);
}